// Round 1
// baseline (290.932 us; speedup 1.0000x reference)
//
#include <hip/hip_runtime.h>
#include <hip/hip_bf16.h>

typedef __bf16 bf16_t;
typedef __bf16 bf16x8 __attribute__((ext_vector_type(8)));
typedef __bf16 bf16x4 __attribute__((ext_vector_type(4)));
typedef float f32x4 __attribute__((ext_vector_type(4)));

#define LDA 264              // padded row stride (bf16 elems): 528B = 16B-aligned, 2-way banks max
#define SMEM_BYTES 142560

// LDS layout (bytes):
//  [0,      33792)  sX   : staged input X (64 x LDA bf16)        } overlaid by per-wave
//  [33792,  67584)  sK   : k all heads (64 x LDA bf16)           }   P buffers (8 x 8KB)
//  [67584, 101376)  sQ   : q all heads; later attn-out x
//  [101376,138240)  sVt  : 8 waves x (32 x 72) bf16, v transposed per head
//  [138240,142304)  rpb  : 127 x 8 f32
//  [142304,142560)  mask : 64 f32
#define OFF_X   0
#define OFF_K   33792
#define OFF_Q   67584
#define OFF_VT  101376
#define OFF_RPB 138240
#define OFF_MSK 142304

__device__ __forceinline__ void stage_x(const float* __restrict__ src, bf16_t* __restrict__ dst, int tid) {
  const float4* s4 = (const float4*)src;
#pragma unroll
  for (int k = 0; k < 8; ++k) {
    int f = tid + (k << 9);           // 4096 float4 total, coalesced
    float4 v = s4[f];
    int row = f >> 6;
    int col = (f & 63) << 2;
    bf16x4 p;
    p[0] = (bf16_t)v.x; p[1] = (bf16_t)v.y; p[2] = (bf16_t)v.z; p[3] = (bf16_t)v.w;
    *(bf16x4*)(dst + row*LDA + col) = p;
  }
}

// y[0:64, cb:cb+32] = A(64x256, LDS) @ W(256x256 bf16 row-major)^T  chunk
__device__ __forceinline__ void gemm_64x32(const bf16_t* __restrict__ A, const bf16_t* __restrict__ W,
                                           int cb, int l15, int g, f32x4 acc[4][2]) {
#pragma unroll
  for (int kt = 0; kt < 8; ++kt) {
    bf16x8 a[4];
#pragma unroll
    for (int mt = 0; mt < 4; ++mt)
      a[mt] = *(const bf16x8*)(A + (mt*16 + l15)*LDA + kt*32 + g*8);
#pragma unroll
    for (int nt = 0; nt < 2; ++nt) {
      bf16x8 bw = *(const bf16x8*)(W + (cb + nt*16 + l15)*256 + kt*32 + g*8);
#pragma unroll
      for (int mt = 0; mt < 4; ++mt)
        acc[mt][nt] = __builtin_amdgcn_mfma_f32_16x16x32_bf16(a[mt], bw, acc[mt][nt], 0, 0, 0);
    }
  }
}

__device__ __forceinline__ void write_frag_rowmajor(bf16_t* __restrict__ dst, const f32x4 acc[4][2],
                                                    float b0, float b1, int cb, int l15, int g) {
#pragma unroll
  for (int mt = 0; mt < 4; ++mt)
#pragma unroll
    for (int nt = 0; nt < 2; ++nt) {
      float bias = nt ? b1 : b0;
#pragma unroll
      for (int r = 0; r < 4; ++r)
        dst[(mt*16 + g*4 + r)*LDA + cb + nt*16 + l15] = (bf16_t)(acc[mt][nt][r] + bias);
    }
}

__global__ __launch_bounds__(512, 2) void chunk_attn_kernel(
    const float* __restrict__ qg, const float* __restrict__ kg, const float* __restrict__ vg,
    const float* __restrict__ maskg, const float* __restrict__ cmg,
    const float* __restrict__ bq, const float* __restrict__ bk, const float* __restrict__ bv,
    const float* __restrict__ bo, const float* __restrict__ rpbg,
    const bf16_t* __restrict__ Wb,   // [4][256*256] bf16: Wq,Wk,Wv,Wo
    float* __restrict__ outg) {
  extern __shared__ char sm[];
  bf16_t* sX   = (bf16_t*)(sm + OFF_X);
  bf16_t* sK   = (bf16_t*)(sm + OFF_K);
  bf16_t* sQ   = (bf16_t*)(sm + OFF_Q);
  float*  sRpb = (float*)(sm + OFF_RPB);
  float*  sMask= (float*)(sm + OFF_MSK);

  const int b    = blockIdx.x;
  const int tid  = threadIdx.x;
  const int wave = tid >> 6;          // = head h
  const int lane = tid & 63;
  const int l15  = lane & 15;
  const int g    = lane >> 4;
  const int cb   = wave << 5;         // feature col base = h*32
  bf16_t* sVt = (bf16_t*)(sm + OFF_VT) + wave * (32*72);
  char*   pW  = sm + wave * 8192;     // P buffer: overlays sX+sK after barrier

  // ---- stage constants + X_q ----
  for (int i = tid; i < 127*8; i += 512) sRpb[i] = rpbg[i];
  if (tid < 64) sMask[tid] = maskg[(b << 6) + tid];
  stage_x(qg + (size_t)b*16384, sX, tid);
  __syncthreads();

  { // q projection -> sQ
    f32x4 acc[4][2] = {};
    gemm_64x32(sX, Wb + 0*65536, cb, l15, g, acc);
    write_frag_rowmajor(sQ, acc, bq[cb + l15], bq[cb + 16 + l15], cb, l15, g);
  }
  __syncthreads();
  stage_x(kg + (size_t)b*16384, sX, tid);
  __syncthreads();
  { // k projection -> sK
    f32x4 acc[4][2] = {};
    gemm_64x32(sX, Wb + 1*65536, cb, l15, g, acc);
    write_frag_rowmajor(sK, acc, bk[cb + l15], bk[cb + 16 + l15], cb, l15, g);
  }
  __syncthreads();
  stage_x(vg + (size_t)b*16384, sX, tid);
  __syncthreads();
  { // v projection -> sVt (transposed per head: vt[d][j] = v[j][d])
    f32x4 acc[4][2] = {};
    gemm_64x32(sX, Wb + 2*65536, cb, l15, g, acc);
    float b0 = bv[cb + l15], b1 = bv[cb + 16 + l15];
#pragma unroll
    for (int nt = 0; nt < 2; ++nt) {
      float bias = nt ? b1 : b0;
#pragma unroll
      for (int mt = 0; mt < 4; ++mt) {
        bf16x4 p;
#pragma unroll
        for (int r = 0; r < 4; ++r) p[r] = (bf16_t)(acc[mt][nt][r] + bias);
        *(bf16x4*)(sVt + (nt*16 + l15)*72 + mt*16 + g*4) = p;
      }
    }
  }

  // ---- scores: S = q_h @ k_h^T (64x64), head h = wave ----
  f32x4 S[4][4];
  {
    bf16x8 aq[4], bkf[4];
#pragma unroll
    for (int mt = 0; mt < 4; ++mt) aq[mt]  = *(const bf16x8*)(sQ + (mt*16 + l15)*LDA + cb + g*8);
#pragma unroll
    for (int nt = 0; nt < 4; ++nt) bkf[nt] = *(const bf16x8*)(sK + (nt*16 + l15)*LDA + cb + g*8);
    const f32x4 z = {};
#pragma unroll
    for (int mt = 0; mt < 4; ++mt)
#pragma unroll
      for (int nt = 0; nt < 4; ++nt)
        S[mt][nt] = __builtin_amdgcn_mfma_f32_16x16x32_bf16(aq[mt], bkf[nt], z, 0, 0, 0);
  }

  // ---- epilogue: scale + rpb + padding mask + chunk mask ----
  // ref: s1 = qk*scale + rpb; s2 = s1*mask; s3 = (s2==0 ? -100 : s2); s4 = s3 + cm
  //  => mask==1: s1 + cm ; mask==0: cm - 100
  const float* cmb = cmg + ((size_t)(b & 127) << 12);
#pragma unroll
  for (int mt = 0; mt < 4; ++mt) {
#pragma unroll
    for (int nt = 0; nt < 4; ++nt) {
      float mj = sMask[nt*16 + l15];
#pragma unroll
      for (int r = 0; r < 4; ++r) {
        int i = mt*16 + g*4 + r;
        int j = nt*16 + l15;
        float cmv = cmb[(i << 6) + j];
        float s1 = S[mt][nt][r] * 0.17677669529663689f + sRpb[((i - j + 63) << 3) + wave];
        S[mt][nt][r] = (mj != 0.0f) ? (s1 + cmv) : (cmv - 100.0f);
      }
    }
  }

  // ---- softmax over j (4 nt in-lane + 16 lanes via shfl_xor) ----
  float rinv[4][4];
#pragma unroll
  for (int mt = 0; mt < 4; ++mt) {
#pragma unroll
    for (int r = 0; r < 4; ++r) {
      float m = fmaxf(fmaxf(S[mt][0][r], S[mt][1][r]), fmaxf(S[mt][2][r], S[mt][3][r]));
      m = fmaxf(m, __shfl_xor(m, 1));
      m = fmaxf(m, __shfl_xor(m, 2));
      m = fmaxf(m, __shfl_xor(m, 4));
      m = fmaxf(m, __shfl_xor(m, 8));
      float sum = 0.0f;
#pragma unroll
      for (int nt = 0; nt < 4; ++nt) {
        float p = __expf(S[mt][nt][r] - m);
        S[mt][nt][r] = p;
        sum += p;
      }
      sum += __shfl_xor(sum, 1);
      sum += __shfl_xor(sum, 2);
      sum += __shfl_xor(sum, 4);
      sum += __shfl_xor(sum, 8);
      rinv[mt][r] = 1.0f / sum;
    }
  }

  __syncthreads();   // all waves done reading sX (v-proj), sK, sQ (scores) -> safe to overlay P

  // ---- write P (unnormalized, bf16) into XOR-swizzled per-wave buffer ----
  // byte = i*128 + ((c ^ (i&7))<<4) + (j&7)*2, c = j>>3  (conflict-free-ish b128 reads)
#pragma unroll
  for (int mt = 0; mt < 4; ++mt)
#pragma unroll
    for (int nt = 0; nt < 4; ++nt)
#pragma unroll
      for (int r = 0; r < 4; ++r) {
        int i = mt*16 + g*4 + r;
        int j = nt*16 + l15;
        int c = j >> 3;
        *(bf16_t*)(pW + i*128 + (((c ^ (i & 7)) << 4) | ((j & 7) << 1))) = (bf16_t)S[mt][nt][r];
      }
  __asm__ volatile("s_waitcnt lgkmcnt(0)" ::: "memory");  // same-wave P RAW safety

  // ---- PV: x_h = P @ v_h (64x32) ----
  f32x4 Xa[4][2] = {};
#pragma unroll
  for (int kt = 0; kt < 2; ++kt) {
    bf16x8 ap[4];
#pragma unroll
    for (int mt = 0; mt < 4; ++mt) {
      int i = mt*16 + l15;
      int c = kt*4 + g;
      ap[mt] = *(const bf16x8*)(pW + i*128 + ((c ^ (i & 7)) << 4));
    }
#pragma unroll
    for (int nt = 0; nt < 2; ++nt) {
      bf16x8 bvf = *(const bf16x8*)(sVt + (nt*16 + l15)*72 + kt*32 + g*8);
#pragma unroll
      for (int mt = 0; mt < 4; ++mt)
        Xa[mt][nt] = __builtin_amdgcn_mfma_f32_16x16x32_bf16(ap[mt], bvf, Xa[mt][nt], 0, 0, 0);
    }
  }

  // ---- normalize + write x back into sQ (overwrites q, safe after barrier above) ----
#pragma unroll
  for (int mt = 0; mt < 4; ++mt)
#pragma unroll
    for (int nt = 0; nt < 2; ++nt)
#pragma unroll
      for (int r = 0; r < 4; ++r)
        sQ[(mt*16 + g*4 + r)*LDA + cb + nt*16 + l15] = (bf16_t)(Xa[mt][nt][r] * rinv[mt][r]);
  __syncthreads();

  // ---- output projection: out = x @ Wo^T + bo ----
  {
    f32x4 acc[4][2] = {};
    gemm_64x32(sQ, Wb + 3*65536, cb, l15, g, acc);
    float b0 = bo[cb + l15], b1 = bo[cb + 16 + l15];
    float* ob = outg + (size_t)b * 16384;
#pragma unroll
    for (int mt = 0; mt < 4; ++mt)
#pragma unroll
      for (int nt = 0; nt < 2; ++nt) {
        float bias = nt ? b1 : b0;
#pragma unroll
        for (int r = 0; r < 4; ++r)
          ob[(mt*16 + g*4 + r)*256 + cb + nt*16 + l15] = acc[mt][nt][r] + bias;
      }
  }
}

__global__ void cvt_weights(const float* __restrict__ Wq, const float* __restrict__ Wk,
                            const float* __restrict__ Wv, const float* __restrict__ Wo,
                            bf16_t* __restrict__ dst) {
  int idx = blockIdx.x * 256 + threadIdx.x;   // 65536 float4 across the 4 matrices
  int which = idx >> 14;
  int off = idx & 16383;
  const float* src = (which == 0) ? Wq : (which == 1) ? Wk : (which == 2) ? Wv : Wo;
  float4 v = ((const float4*)src)[off];
  bf16x4 p;
  p[0] = (bf16_t)v.x; p[1] = (bf16_t)v.y; p[2] = (bf16_t)v.z; p[3] = (bf16_t)v.w;
  *(bf16x4*)(dst + which*65536 + off*4) = p;
}

extern "C" void kernel_launch(void* const* d_in, const int* in_sizes, int n_in,
                              void* d_out, int out_size, void* d_ws, size_t ws_size,
                              hipStream_t stream) {
  (void)in_sizes; (void)n_in; (void)out_size; (void)ws_size;
  const float* qg  = (const float*)d_in[0];
  const float* kg  = (const float*)d_in[1];
  const float* vg  = (const float*)d_in[2];
  const float* mg  = (const float*)d_in[3];
  const float* cmg = (const float*)d_in[4];
  const float* Wq  = (const float*)d_in[5];
  const float* bq  = (const float*)d_in[6];
  const float* Wk  = (const float*)d_in[7];
  const float* bk  = (const float*)d_in[8];
  const float* Wv  = (const float*)d_in[9];
  const float* bv  = (const float*)d_in[10];
  const float* Wo  = (const float*)d_in[11];
  const float* bo  = (const float*)d_in[12];
  const float* rpb = (const float*)d_in[13];
  bf16_t* Wb = (bf16_t*)d_ws;            // 4 * 65536 bf16 = 512 KB
  float* outg = (float*)d_out;

  hipFuncSetAttribute(reinterpret_cast<const void*>(chunk_attn_kernel),
                      hipFuncAttributeMaxDynamicSharedMemorySize, SMEM_BYTES);
  cvt_weights<<<256, 256, 0, stream>>>(Wq, Wk, Wv, Wo, Wb);
  chunk_attn_kernel<<<2048, 512, SMEM_BYTES, stream>>>(qg, kg, vg, mg, cmg,
      bq, bk, bv, bo, rpb, Wb, outg);
}